// Round 3
// baseline (743.343 us; speedup 1.0000x reference)
//
#include <hip/hip_runtime.h>
#include <hip/hip_bf16.h>
#include <math.h>

// Problem constants
#define B_    8
#define S_    512
#define H_    768
#define HID_  384
#define G3_   1152      // 3*HID
#define ENT_  52
#define INNER_ 64
#define NOUT_ 6656      // ENT*2*INNER
#define K1_   1536
#define KA_   768       // lhs part of K
#define BIG_  1000000000000.0f

#define TILE_BYTES 8192            // one 128x32 bf16 tile
#define A_BLK_BYTES (32u*24u*8192u)   // 6,291,456
#define B_BLK_BYTES (52u*24u*8192u)   // 10,223,616
#define QK_BLK_BYTES (8u*52u*4u*2u*8192u) // 27,262,976

typedef __attribute__((ext_vector_type(8))) short bf16x8;
typedef __attribute__((ext_vector_type(4))) float f32x4;

// RN hi + truncated lo split: x ~= hi + lo to ~2^-17 relative.
__device__ __forceinline__ void splitbf(float x, unsigned& h, unsigned& l) {
    unsigned u = __float_as_uint(x);
    unsigned t = u + 0x7fffu + ((u >> 16) & 1u);
    h = t >> 16;
    float hif = __uint_as_float(t & 0xffff0000u);
    l = __float_as_uint(x - hif) >> 16;
}

// async global->LDS, 16B per lane; LDS dest is wave-uniform base + lane*16.
__device__ __forceinline__ void gl16(const void* g, void* l) {
    __builtin_amdgcn_global_load_lds((__attribute__((address_space(1))) void*)g,
                                     (__attribute__((address_space(3))) void*)l,
                                     16, 0, 0);
}

// swizzled byte offset inside a 128x32 bf16 tile (row r, bf16 col kk)
__device__ __forceinline__ int tswz(int r, int kk) {
    return (r * 64 + kk * 2) ^ ((r & 7) << 4);
}

// ---------------------------------------------------------------------------
// RoPE cos/sin table: tab[s][i] = {cos, sin}, i in [0,32)
// ---------------------------------------------------------------------------
__global__ void rope_table_k(float* __restrict__ tab) {
    int idx = blockIdx.x * blockDim.x + threadIdx.x;
    if (idx >= S_ * 32) return;
    int s = idx >> 5;
    int i = idx & 31;
    float invf = powf(10000.0f, -2.0f * (float)i / 64.0f);
    float ang = (float)s * invf;
    tab[idx * 2 + 0] = cosf(ang);
    tab[idx * 2 + 1] = sinf(ang);
}

// ---------------------------------------------------------------------------
// Pre-convert lhs (4096 x 768 fp32) -> hi/lo bf16, tile-blocked [bm][kt][swz 8KB]
// ---------------------------------------------------------------------------
__global__ void convert_lhs_k(const float* __restrict__ lhs,
                              char* __restrict__ Ah, char* __restrict__ Al) {
    int m = blockIdx.x;
    int t = threadIdx.x;
    float4 v = *reinterpret_cast<const float4*>(&lhs[(size_t)m * KA_ + t * 4]);
    unsigned h0,l0,h1,l1,h2,l2,h3,l3;
    splitbf(v.x, h0, l0); splitbf(v.y, h1, l1);
    splitbf(v.z, h2, l2); splitbf(v.w, h3, l3);
    int bm = m >> 7, r = m & 127;
    int kt = t >> 3, kk = (t & 7) * 4;
    size_t base = ((size_t)bm * 24 + kt) * TILE_BYTES;
    int off = tswz(r, kk);
    uint2 hv = make_uint2(h0 | (h1 << 16), h2 | (h3 << 16));
    uint2 lv = make_uint2(l0 | (l1 << 16), l2 | (l3 << 16));
    *reinterpret_cast<uint2*>(Ah + base + off) = hv;
    *reinterpret_cast<uint2*>(Al + base + off) = lv;
}

// ---------------------------------------------------------------------------
// Pre-convert dense_w[:, :768] -> hi/lo bf16, blocked [bn][kt][swz 8KB]
// ---------------------------------------------------------------------------
__global__ void convert_dw_k(const float* __restrict__ dw,
                             char* __restrict__ Bh, char* __restrict__ Bl) {
    int n = blockIdx.x;
    int t = threadIdx.x;
    float4 v = *reinterpret_cast<const float4*>(&dw[(size_t)n * K1_ + t * 4]);
    unsigned h0,l0,h1,l1,h2,l2,h3,l3;
    splitbf(v.x, h0, l0); splitbf(v.y, h1, l1);
    splitbf(v.z, h2, l2); splitbf(v.w, h3, l3);
    int bn = n >> 7, r = n & 127;
    int kt = t >> 3, kk = (t & 7) * 4;
    size_t base = ((size_t)bn * 24 + kt) * TILE_BYTES;
    int off = tswz(r, kk);
    uint2 hv = make_uint2(h0 | (h1 << 16), h2 | (h3 << 16));
    uint2 lv = make_uint2(l0 | (l1 << 16), l2 | (l3 << 16));
    *reinterpret_cast<uint2*>(Bh + base + off) = hv;
    *reinterpret_cast<uint2*>(Bl + base + off) = lv;
}

// ---------------------------------------------------------------------------
// GRU GEMMs (unchanged from passing baseline)
// ---------------------------------------------------------------------------
__global__ void gru_gemm_k(const float* __restrict__ cls,
                           const float* __restrict__ h0,
                           const float* __restrict__ wihf, const float* __restrict__ whhf,
                           const float* __restrict__ bihf, const float* __restrict__ bhhf,
                           const float* __restrict__ wihb, const float* __restrict__ whhb,
                           const float* __restrict__ bihb, const float* __restrict__ bhhb,
                           float* __restrict__ gi, float* __restrict__ gh) {
    int wave = blockIdx.x * (blockDim.x >> 6) + (threadIdx.x >> 6);
    int lane = threadIdx.x & 63;
    if (wave >= 2 * G3_) return;
    int dir = wave / G3_;
    int j = wave % G3_;
    const float* wih = dir ? wihb : wihf;
    const float* whh = dir ? whhb : whhf;
    const float* bih = dir ? bihb : bihf;
    const float* bhh = dir ? bhhb : bhhf;

    float ai[B_], ah[B_];
#pragma unroll
    for (int b = 0; b < B_; ++b) { ai[b] = 0.f; ah[b] = 0.f; }
    for (int k = lane; k < H_; k += 64) {
        float w = wih[j * H_ + k];
#pragma unroll
        for (int b = 0; b < B_; ++b) ai[b] += w * cls[b * H_ + k];
    }
    for (int k = lane; k < HID_; k += 64) {
        float w = whh[j * HID_ + k];
#pragma unroll
        for (int b = 0; b < B_; ++b) ah[b] += w * h0[(dir * B_ + b) * HID_ + k];
    }
#pragma unroll
    for (int off = 32; off > 0; off >>= 1) {
#pragma unroll
        for (int b = 0; b < B_; ++b) {
            ai[b] += __shfl_xor(ai[b], off);
            ah[b] += __shfl_xor(ah[b], off);
        }
    }
    if (lane == 0) {
#pragma unroll
        for (int b = 0; b < B_; ++b) {
            gi[(dir * B_ + b) * G3_ + j] = ai[b] + bih[j];
            gh[(dir * B_ + b) * G3_ + j] = ah[b] + bhh[j];
        }
    }
}

__global__ void gru_combine_k(const float* __restrict__ gi, const float* __restrict__ gh,
                              const float* __restrict__ h0, float* __restrict__ cls_emb) {
    int idx = blockIdx.x * blockDim.x + threadIdx.x;
    if (idx >= 2 * B_ * HID_) return;
    int dir = idx / (B_ * HID_);
    int r = idx % (B_ * HID_);
    int b = r / HID_;
    int h = r % HID_;
    const float* giP = gi + (dir * B_ + b) * G3_;
    const float* ghP = gh + (dir * B_ + b) * G3_;
    float ir = giP[h],        hr = ghP[h];
    float iz = giP[HID_ + h], hz = ghP[HID_ + h];
    float in_ = giP[2 * HID_ + h], hn = ghP[2 * HID_ + h];
    float rr = 1.f / (1.f + expf(-(ir + hr)));
    float z  = 1.f / (1.f + expf(-(iz + hz)));
    float n  = tanhf(in_ + rr * hn);
    float hp = h0[(dir * B_ + b) * HID_ + h];
    cls_emb[b * H_ + dir * HID_ + h] = (1.f - z) * n + z * hp;
}

__global__ void cls_ctr_k(const float* __restrict__ cls_emb,
                          const float* __restrict__ dw, const float* __restrict__ db,
                          float* __restrict__ ctr) {
    int wave = blockIdx.x * (blockDim.x >> 6) + (threadIdx.x >> 6);
    int lane = threadIdx.x & 63;
    if (wave >= NOUT_) return;
    const float* w = dw + (size_t)wave * K1_ + KA_;
    float a[B_];
#pragma unroll
    for (int b = 0; b < B_; ++b) a[b] = 0.f;
    for (int k = lane; k < H_; k += 64) {
        float ww = w[k];
#pragma unroll
        for (int b = 0; b < B_; ++b) a[b] += ww * cls_emb[b * H_ + k];
    }
#pragma unroll
    for (int off = 32; off > 0; off >>= 1) {
#pragma unroll
        for (int b = 0; b < B_; ++b) a[b] += __shfl_xor(a[b], off);
    }
    if (lane == 0) {
#pragma unroll
        for (int b = 0; b < B_; ++b) ctr[b * NOUT_ + wave] = a[b] + db[wave];
    }
}

// ---------------------------------------------------------------------------
// Dense GEMM, bf16x3 MFMA, OPERANDS SWAPPED (A=dense_w rows, B=lhs rows) so
// D rows = features -> RoPE pairs are in-register, stores are uint2.
// 128x128 tile, BK=32, 4 waves (wr = s-half, wc = q/k feature half).
// Grid (52, 32) with bijective XCD-chunked remap.
// ---------------------------------------------------------------------------
__global__ __launch_bounds__(256, 3)
void dense_mfma_k(const char* __restrict__ Ahb, const char* __restrict__ Alb,
                  const char* __restrict__ Bhb, const char* __restrict__ Blb,
                  const float* __restrict__ ctr, const float* __restrict__ rope,
                  char* __restrict__ qh, char* __restrict__ ql,
                  char* __restrict__ kh, char* __restrict__ kl) {
    __shared__ __align__(16) char lds[32768];
    char* ldsAh = lds;
    char* ldsAl = lds + 8192;
    char* ldsBh = lds + 16384;
    char* ldsBl = lds + 24576;

    int tid = threadIdx.x;
    int w = tid >> 6, lane = tid & 63;
    int l15 = lane & 15, l4 = lane >> 4;
    int wr = w >> 1, wc = w & 1;

    // XCD-chunked bijective remap (1664 = 8 * 208)
    int flat = blockIdx.x + 52 * blockIdx.y;
    int nb = (flat & 7) * 208 + (flat >> 3);
    int bn = nb % 52, bm = nb / 52;

    f32x4 acc[4][4] = {};

    const char* Ah0 = Ahb + (size_t)bm * 24 * TILE_BYTES;
    const char* Al0 = Alb + (size_t)bm * 24 * TILE_BYTES;
    const char* Bh0 = Bhb + (size_t)bn * 24 * TILE_BYTES;
    const char* Bl0 = Blb + (size_t)bn * 24 * TILE_BYTES;

    int c0 = w * 1024 + lane * 16;
    int c1 = c0 + 4096;
    int d0 = w * 1024, d1 = d0 + 4096;

    for (int kt = 0; kt < 24; ++kt) {
        size_t tb = (size_t)kt * TILE_BYTES;
        gl16(Ah0 + tb + c0, ldsAh + d0); gl16(Ah0 + tb + c1, ldsAh + d1);
        gl16(Al0 + tb + c0, ldsAl + d0); gl16(Al0 + tb + c1, ldsAl + d1);
        gl16(Bh0 + tb + c0, ldsBh + d0); gl16(Bh0 + tb + c1, ldsBh + d1);
        gl16(Bl0 + tb + c0, ldsBl + d0); gl16(Bl0 + tb + c1, ldsBl + d1);
        __syncthreads();

        // lhs fragments (B-operand), ni = s-frag
        bf16x8 lh[4], ll[4];
#pragma unroll
        for (int ni = 0; ni < 4; ++ni) {
            int row = wr * 64 + ni * 16 + l15;
            int off = (row * 64 + l4 * 16) ^ ((row & 7) << 4);
            lh[ni] = *reinterpret_cast<const bf16x8*>(ldsAh + off);
            ll[ni] = *reinterpret_cast<const bf16x8*>(ldsAl + off);
        }
        // weight fragments (A-operand) loaded per-mi to cap liveness
#pragma unroll
        for (int mi = 0; mi < 4; ++mi) {
            int row = wc * 64 + mi * 16 + l15;
            int off = (row * 64 + l4 * 16) ^ ((row & 7) << 4);
            bf16x8 wh = *reinterpret_cast<const bf16x8*>(ldsBh + off);
            bf16x8 wl = *reinterpret_cast<const bf16x8*>(ldsBl + off);
#pragma unroll
            for (int ni = 0; ni < 4; ++ni) {
                acc[mi][ni] = __builtin_amdgcn_mfma_f32_16x16x32_bf16(wh, lh[ni], acc[mi][ni], 0, 0, 0);
                acc[mi][ni] = __builtin_amdgcn_mfma_f32_16x16x32_bf16(wh, ll[ni], acc[mi][ni], 0, 0, 0);
                acc[mi][ni] = __builtin_amdgcn_mfma_f32_16x16x32_bf16(wl, lh[ni], acc[mi][ni], 0, 0, 0);
            }
        }
        __syncthreads();
    }

    // Epilogue: D[feature d][s]. d = wc*64 + mi*16 + l4*4 + j ; s-row = wr*64 + ni*16 + l15
    int b = bm >> 2;
    int tm = bm & 3;
    int ent = bn;
    char* DH = wc ? kh : qh;
    char* DL = wc ? kl : ql;
    size_t panel = (size_t)b * ENT_ + ent;
    const float2* rope2 = reinterpret_cast<const float2*>(rope);

#pragma unroll
    for (int mi = 0; mi < 4; ++mi) {
        int dq0 = mi * 16 + l4 * 4;          // 0..63 within q (or k)
        int ktq = dq0 >> 5, kk = dq0 & 31;
        float4 cv = *reinterpret_cast<const float4*>(
            &ctr[b * NOUT_ + ent * 128 + wc * 64 + dq0]);
        size_t tbase = ((panel * 4 + tm) * 2 + ktq) * TILE_BYTES;
#pragma unroll
        for (int ni = 0; ni < 4; ++ni) {
            int r = wr * 64 + ni * 16 + l15;   // row within 128 s-tile
            int s = tm * 128 + r;
            float2 cs01 = rope2[s * 32 + (dq0 >> 1)];
            float2 cs23 = rope2[s * 32 + (dq0 >> 1) + 1];
            float v0 = acc[mi][ni][0] + cv.x;
            float v1 = acc[mi][ni][1] + cv.y;
            float v2 = acc[mi][ni][2] + cv.z;
            float v3 = acc[mi][ni][3] + cv.w;
            float o0 = v0 * cs01.x - v1 * cs01.y;
            float o1 = v1 * cs01.x + v0 * cs01.y;
            float o2 = v2 * cs23.x - v3 * cs23.y;
            float o3 = v3 * cs23.x + v2 * cs23.y;
            unsigned h0,l0,h1,l1,h2,l2,h3,l3;
            splitbf(o0, h0, l0); splitbf(o1, h1, l1);
            splitbf(o2, h2, l2); splitbf(o3, h3, l3);
            int off = tswz(r, kk);
            *reinterpret_cast<uint2*>(DH + tbase + off) =
                make_uint2(h0 | (h1 << 16), h2 | (h3 << 16));
            *reinterpret_cast<uint2*>(DL + tbase + off) =
                make_uint2(l0 | (l1 << 16), l2 | (l3 << 16));
        }
    }
}

// ---------------------------------------------------------------------------
// Logits, bf16x3 MFMA, OPERANDS SWAPPED (A=K rows -> D rows = n) for float4
// stores. One block per (b, h, tm): Q frags cached in registers, K tiles
// staged per tn. Grid (4, 52, 8) with XCD-chunked remap.
// ---------------------------------------------------------------------------
__global__ __launch_bounds__(256)
void logits_mfma_k(const char* __restrict__ qh, const char* __restrict__ ql,
                   const char* __restrict__ kh, const char* __restrict__ kl,
                   const float* __restrict__ mask, float* __restrict__ out) {
    __shared__ __align__(16) char lds[32768];
    char* ldsKh = lds;            // [2][8192]
    char* ldsKl = lds + 16384;    // [2][8192]

    int tid = threadIdx.x;
    int w = tid >> 6, lane = tid & 63;
    int l15 = lane & 15, l4 = lane >> 4;
    int wr = w >> 1, wc = w & 1;   // wr = n-half, wc = m-half

    int flat = blockIdx.x + 4 * (blockIdx.y + 52 * blockIdx.z);
    int nb = (flat & 7) * 208 + (flat >> 3);
    int tm = nb & 3;
    int t2 = nb >> 2;
    int hh = t2 % 52, bb = t2 / 52;
    size_t panel = (size_t)bb * ENT_ + hh;

    // Load Q fragments once (B-operand): qf[kt][mi], m-row = wc*64+mi*16+l15
    bf16x8 qf_h[2][4], qf_l[2][4];
    {
        const char* Qh0 = qh + (panel * 4 + tm) * 2 * TILE_BYTES;
        const char* Ql0 = ql + (panel * 4 + tm) * 2 * TILE_BYTES;
#pragma unroll
        for (int kt = 0; kt < 2; ++kt) {
#pragma unroll
            for (int mi = 0; mi < 4; ++mi) {
                int r = wc * 64 + mi * 16 + l15;
                int off = kt * TILE_BYTES + tswz(r, l4 * 8);
                qf_h[kt][mi] = *reinterpret_cast<const bf16x8*>(Qh0 + off);
                qf_l[kt][mi] = *reinterpret_cast<const bf16x8*>(Ql0 + off);
            }
        }
    }

    int c0 = w * 1024 + lane * 16;
    int c1 = c0 + 4096;
    int d0 = w * 1024, d1 = d0 + 4096;
    size_t obase = panel * (size_t)(S_ * S_);
    int m = tm * 128 + wc * 64 + l15;   // + mi*16

    for (int tn = 0; tn < 4; ++tn) {
        const char* Kh0 = kh + (panel * 4 + tn) * 2 * TILE_BYTES;
        const char* Kl0 = kl + (panel * 4 + tn) * 2 * TILE_BYTES;
#pragma unroll
        for (int kt = 0; kt < 2; ++kt) {
            gl16(Kh0 + kt * TILE_BYTES + c0, ldsKh + kt * TILE_BYTES + d0);
            gl16(Kh0 + kt * TILE_BYTES + c1, ldsKh + kt * TILE_BYTES + d1);
            gl16(Kl0 + kt * TILE_BYTES + c0, ldsKl + kt * TILE_BYTES + d0);
            gl16(Kl0 + kt * TILE_BYTES + c1, ldsKl + kt * TILE_BYTES + d1);
        }
        __syncthreads();

        f32x4 acc[4][4] = {};
#pragma unroll
        for (int kt = 0; kt < 2; ++kt) {
#pragma unroll
            for (int ni = 0; ni < 4; ++ni) {
                int r = wr * 64 + ni * 16 + l15;   // n-row within 128 tile
                int off = kt * TILE_BYTES + tswz(r, l4 * 8);
                bf16x8 ah = *reinterpret_cast<const bf16x8*>(ldsKh + off);
                bf16x8 al = *reinterpret_cast<const bf16x8*>(ldsKl + off);
#pragma unroll
                for (int mi = 0; mi < 4; ++mi) {
                    acc[mi][ni] = __builtin_amdgcn_mfma_f32_16x16x32_bf16(ah, qf_h[kt][mi], acc[mi][ni], 0, 0, 0);
                    acc[mi][ni] = __builtin_amdgcn_mfma_f32_16x16x32_bf16(ah, qf_l[kt][mi], acc[mi][ni], 0, 0, 0);
                    acc[mi][ni] = __builtin_amdgcn_mfma_f32_16x16x32_bf16(al, qf_h[kt][mi], acc[mi][ni], 0, 0, 0);
                }
            }
        }

        // Epilogue: n = tn*128 + wr*64 + ni*16 + l4*4 + j ; m = tm*128+wc*64+mi*16+l15
#pragma unroll
        for (int ni = 0; ni < 4; ++ni) {
            int n0 = tn * 128 + wr * 64 + ni * 16 + l4 * 4;
            float4 p4 = *reinterpret_cast<const float4*>(&mask[bb * S_ + n0]);
            const float* pv = reinterpret_cast<const float*>(&p4);
#pragma unroll
            for (int mi = 0; mi < 4; ++mi) {
                int mm = m + mi * 16;
                float4 o;
                float* ov = reinterpret_cast<float*>(&o);
#pragma unroll
                for (int j = 0; j < 4; ++j) {
                    float val = acc[mi][ni][j];
                    float p = pv[j];
                    val = val * p - (1.0f - p) * BIG_;
                    if (n0 + j < mm) val -= BIG_;
                    ov[j] = val * 0.125f;
                }
                *reinterpret_cast<float4*>(&out[obase + (size_t)mm * S_ + n0]) = o;
            }
        }
        __syncthreads();
    }
}

// ---------------------------------------------------------------------------
extern "C" void kernel_launch(void* const* d_in, const int* in_sizes, int n_in,
                              void* d_out, int out_size, void* d_ws, size_t ws_size,
                              hipStream_t stream) {
    const float* lhs  = (const float*)d_in[0];
    const float* cls  = (const float*)d_in[1];
    const float* h0   = (const float*)d_in[2];
    const float* mask = (const float*)d_in[3];
    const float* wihf = (const float*)d_in[4];
    const float* whhf = (const float*)d_in[5];
    const float* bihf = (const float*)d_in[6];
    const float* bhhf = (const float*)d_in[7];
    const float* wihb = (const float*)d_in[8];
    const float* whhb = (const float*)d_in[9];
    const float* bihb = (const float*)d_in[10];
    const float* bhhb = (const float*)d_in[11];
    const float* dw   = (const float*)d_in[12];
    const float* db   = (const float*)d_in[13];
    float* out = (float*)d_out;

    char* p = (char*)d_ws;
    char* Ahb = p;  p += A_BLK_BYTES;
    char* Alb = p;  p += A_BLK_BYTES;
    char* Bhb = p;  p += B_BLK_BYTES;
    char* Blb = p;  p += B_BLK_BYTES;
    char* qhb = p;  p += QK_BLK_BYTES;
    char* qlb = p;  p += QK_BLK_BYTES;
    char* khb = p;  p += QK_BLK_BYTES;
    char* klb = p;  p += QK_BLK_BYTES;
    float* gi      = (float*)p;
    float* gh      = gi + 2 * B_ * G3_;
    float* cls_emb = gh + 2 * B_ * G3_;
    float* ctr     = cls_emb + B_ * H_;
    float* rope    = ctr + B_ * NOUT_;

    rope_table_k<<<64, 256, 0, stream>>>(rope);
    convert_lhs_k<<<4096, 192, 0, stream>>>(lhs, Ahb, Alb);
    convert_dw_k<<<6656, 192, 0, stream>>>(dw, Bhb, Blb);
    gru_gemm_k<<<576, 256, 0, stream>>>(cls, h0, wihf, whhf, bihf, bhhf,
                                        wihb, whhb, bihb, bhhb, gi, gh);
    gru_combine_k<<<24, 256, 0, stream>>>(gi, gh, h0, cls_emb);
    cls_ctr_k<<<NOUT_ / 4, 256, 0, stream>>>(cls_emb, dw, db, ctr);
    dense_mfma_k<<<dim3(ENT_, 32), 256, 0, stream>>>(Ahb, Alb, Bhb, Blb,
                                                     ctr, rope, qhb, qlb, khb, klb);
    logits_mfma_k<<<dim3(4, ENT_, B_), 256, 0, stream>>>(qhb, qlb, khb, klb, mask, out);
}